// Round 7
// baseline (503.208 us; speedup 1.0000x reference)
//
#include <hip/hip_runtime.h>
#include <math.h>

typedef short s16x8 __attribute__((ext_vector_type(8)));
typedef float f32x4 __attribute__((ext_vector_type(4)));
typedef unsigned short u16x4 __attribute__((ext_vector_type(4)));
typedef unsigned short u16x8 __attribute__((ext_vector_type(8)));

#define DIM_ 768
#define HID_ 3072
#define NTOK 4096
#define CAP 9216

__device__ __forceinline__ unsigned short f2bf(float f) {
  unsigned u = __float_as_uint(f);
  u += 0x7fffu + ((u >> 16) & 1u);   // RNE
  return (unsigned short)(u >> 16);
}
__device__ __forceinline__ float bf2f(unsigned short u) {
  return __uint_as_float(((unsigned)u) << 16);
}

__device__ __forceinline__ void async_cp16(const void* g, void* l) {
  __builtin_amdgcn_global_load_lds(
      (const __attribute__((address_space(1))) void*)g,
      (__attribute__((address_space(3))) void*)l, 16, 0, 0);
}

__device__ __forceinline__ void cvt2048(const float* __restrict__ s,
                                        unsigned short* __restrict__ d, long i) {
  float4 a = *(const float4*)(s + i);
  float4 b = *(const float4*)(s + i + 4);
  u16x8 o;
  o[0]=f2bf(a.x); o[1]=f2bf(a.y); o[2]=f2bf(a.z); o[3]=f2bf(a.w);
  o[4]=f2bf(b.x); o[5]=f2bf(b.y); o[6]=f2bf(b.z); o[7]=f2bf(b.w);
  *(u16x8*)(d + i) = o;
}

// ---------------- 128x128 bf16 MFMA GEMM mainloop (R3 structure, proven) --
template<bool BBF>
__device__ __forceinline__ void gemm_loop(
    const unsigned short* aS0, const unsigned short* aS1,
    const void* __restrict__ Bv, int ldb,
    int kbeg, int kend, int col0,
    unsigned short* lA, unsigned short* lB,   // each 2*4096 elements
    f32x4 acc[4][4])
{
  const int tid = threadIdx.x;
  const int lane = tid & 63;
  const int w = tid >> 6;
  const int wm = (w >> 1) << 6;
  const int wn = (w & 1) << 6;
  const int g = lane >> 4;
  const int lm = lane & 15;

  if constexpr (BBF) {
    const unsigned short* Bb = (const unsigned short*)Bv;
    const unsigned short* bS[2];
#pragma unroll
    for (int it = 0; it < 2; ++it) {
      int c = (w * 2 + it) * 64 + lane;
      int r = c >> 2, ks = ((c & 3) ^ ((r >> 1) & 3)) << 3;
      bS[it] = Bb + (size_t)(col0 + r) * ldb + ks;
    }
    auto stage = [&](int k0, int p) {
      async_cp16(aS0 + k0, lA + p * 4096 + (w * 2 + 0) * 512);
      async_cp16(bS[0] + k0, lB + p * 4096 + (w * 2 + 0) * 512);
      async_cp16(aS1 + k0, lA + p * 4096 + (w * 2 + 1) * 512);
      async_cp16(bS[1] + k0, lB + p * 4096 + (w * 2 + 1) * 512);
    };
    stage(kbeg, 0);
    int p = 0;
    for (int k0 = kbeg; k0 < kend; k0 += 32) {
      __syncthreads();                       // buf p staged
      if (k0 + 32 < kend) stage(k0 + 32, p ^ 1);
      const unsigned short* bA = lA + p * 4096;
      const unsigned short* bB = lB + p * 4096;
      s16x8 a_frag[4], b_frag[4];
#pragma unroll
      for (int mt = 0; mt < 4; ++mt) {
        int ra = wm + mt * 16 + lm;
        a_frag[mt] = *(const s16x8*)(bA + ra * 32 + ((g ^ ((ra >> 1) & 3)) << 3));
      }
#pragma unroll
      for (int nt = 0; nt < 4; ++nt) {
        int cb = wn + nt * 16 + lm;
        b_frag[nt] = *(const s16x8*)(bB + cb * 32 + ((g ^ ((cb >> 1) & 3)) << 3));
      }
#pragma unroll
      for (int mt = 0; mt < 4; ++mt)
#pragma unroll
        for (int nt = 0; nt < 4; ++nt)
          acc[mt][nt] = __builtin_amdgcn_mfma_f32_16x16x32_bf16(
              a_frag[mt], b_frag[nt], acc[mt][nt], 0, 0, 0);
      p ^= 1;
    }
  } else {
    const float* Bf = (const float*)Bv;
    for (int k0 = kbeg; k0 < kend; k0 += 32) {
      __syncthreads();
      async_cp16(aS0 + k0, lA + (w * 2 + 0) * 512);
      async_cp16(aS1 + k0, lA + (w * 2 + 1) * 512);
#pragma unroll
      for (int it = 0; it < 4; ++it) {
        int f = it * 1024 + tid * 4;
        int br = f >> 5, ke = f & 31;
        const float4 vv = *(const float4*)(Bf + (size_t)(col0 + br) * ldb + (k0 + ke));
        u16x4 pk;
        pk[0] = f2bf(vv.x); pk[1] = f2bf(vv.y); pk[2] = f2bf(vv.z); pk[3] = f2bf(vv.w);
        int ksw = (((ke >> 3) ^ ((br >> 1) & 3)) << 3) + (ke & 7);
        *(u16x4*)(lB + br * 32 + ksw) = pk;
      }
      __syncthreads();
      s16x8 a_frag[4], b_frag[4];
#pragma unroll
      for (int mt = 0; mt < 4; ++mt) {
        int ra = wm + mt * 16 + lm;
        a_frag[mt] = *(const s16x8*)(lA + ra * 32 + ((g ^ ((ra >> 1) & 3)) << 3));
      }
#pragma unroll
      for (int nt = 0; nt < 4; ++nt) {
        int cb = wn + nt * 16 + lm;
        b_frag[nt] = *(const s16x8*)(lB + cb * 32 + ((g ^ ((cb >> 1) & 3)) << 3));
      }
#pragma unroll
      for (int mt = 0; mt < 4; ++mt)
#pragma unroll
        for (int nt = 0; nt < 4; ++nt)
          acc[mt][nt] = __builtin_amdgcn_mfma_f32_16x16x32_bf16(
              a_frag[mt], b_frag[nt], acc[mt][nt], 0, 0, 0);
    }
  }
}

#define GEMM_PROLOGUE                                   \
  __shared__ unsigned short lA[8192];                   \
  __shared__ unsigned short lB[8192];                   \
  f32x4 acc[4][4];                                      \
  _Pragma("unroll") for (int a_ = 0; a_ < 4; ++a_)      \
  _Pragma("unroll") for (int b_ = 0; b_ < 4; ++b_) {    \
    acc[a_][b_][0]=0.f; acc[a_][b_][1]=0.f;             \
    acc[a_][b_][2]=0.f; acc[a_][b_][3]=0.f; }           \
  const int lane = threadIdx.x & 63;                    \
  const int w = threadIdx.x >> 6;                       \
  const int wm = (w >> 1) << 6, wn = (w & 1) << 6;      \
  const int g = lane >> 4, lm = lane & 15;

#define A_PTRS(Abase, LDA)                                            \
  const unsigned short* aS[2];                                        \
  _Pragma("unroll") for (int it_ = 0; it_ < 2; ++it_) {               \
    int c_ = (w * 2 + it_) * 64 + lane;                               \
    int r_ = c_ >> 2, ks_ = ((c_ & 3) ^ ((r_ >> 1) & 3)) << 3;        \
    aS[it_] = (Abase) + (size_t)(row0 + r_) * (LDA) + ks_;            \
  }

// ---------------- kernels -------------------------------------------------

// fused: qkvw+projw convert (blocks < 1152) + LayerNorm1 (the rest).
__global__ void k_cvtln(const float* __restrict__ s0, const float* __restrict__ s1,
                        unsigned short* __restrict__ d0, unsigned short* __restrict__ d1,
                        const float* __restrict__ x, const float* __restrict__ gg,
                        const float* __restrict__ bb, unsigned short* __restrict__ outb)
{
  __shared__ float red[8];
  if ((int)blockIdx.x < 1152) {
    long i = (long)(blockIdx.x * 256 + threadIdx.x) * 8;
    if (i < 1769472) cvt2048(s0, d0, i);
    else             cvt2048(s1 - 1769472, d1 - 1769472, i);
    return;
  }
  int t = blockIdx.x - 1152, tid = threadIdx.x;
  const float* xr = x + (size_t)t * DIM_;
  float v0 = xr[tid], v1 = xr[tid + 256], v2 = xr[tid + 512];
  float s = v0 + v1 + v2, q = v0 * v0 + v1 * v1 + v2 * v2;
  for (int o = 32; o; o >>= 1) { s += __shfl_xor(s, o, 64); q += __shfl_xor(q, o, 64); }
  int lane = tid & 63, w = tid >> 6;
  if (!lane) { red[w] = s; red[4 + w] = q; }
  __syncthreads();
  s = red[0] + red[1] + red[2] + red[3];
  q = red[4] + red[5] + red[6] + red[7];
  float mean = s * (1.f / 768.f);
  float rstd = rsqrtf(q * (1.f / 768.f) - mean * mean + 1e-5f);
  unsigned short* orow = outb + (size_t)t * DIM_;
  orow[tid]       = f2bf((v0 - mean) * rstd * gg[tid]       + bb[tid]);
  orow[tid + 256] = f2bf((v1 - mean) * rstd * gg[tid + 256] + bb[tid + 256]);
  orow[tid + 512] = f2bf((v2 - mean) * rstd * gg[tid + 512] + bb[tid + 512]);
}

// blocks 0..575: qkv GEMM (XCD-swizzled). blocks 576+: w1/w2 fp32->bf16
// convert, co-resident with the GEMM (LDS 32KB allows 5 blocks/CU, GEMM
// only occupies ~2.25) so conversion rides the idle HBM bandwidth.
template<bool FULL>
__global__ __launch_bounds__(256, 4) void k_qkvcvt(
    const unsigned short* __restrict__ hbf, const void* __restrict__ qkvw,
    unsigned short* __restrict__ qkvb,
    const float* __restrict__ w1f, const float* __restrict__ w2f,
    unsigned short* __restrict__ w1bf, unsigned short* __restrict__ w2bf)
{
  GEMM_PROLOGUE
  if constexpr (FULL) {
    if ((int)blockIdx.x >= 576) {
      int c2 = blockIdx.x - 576;
      if (c2 < 9216) cvt2048(w1f, w1bf, (long)c2 * 2048 + threadIdx.x * 8);
      else           cvt2048(w2f, w2bf, (long)(c2 - 9216) * 2048 + threadIdx.x * 8);
      return;
    }
  }
  int f = blockIdx.x, xcd = f & 7, s = f >> 3;
  int cg = s / 24, rr = (s % 24) / 6, c = cg * 6 + s % 6;
  int row0 = (xcd * 4 + rr) * 128, col0 = c * 128;
  A_PTRS(hbf, DIM_)
  gemm_loop<true>(aS[0], aS[1], qkvw, DIM_, 0, DIM_, col0, lA, lB, acc);
#pragma unroll
  for (int mt = 0; mt < 4; ++mt)
#pragma unroll
    for (int nt = 0; nt < 4; ++nt)
#pragma unroll
      for (int i = 0; i < 4; ++i) {
        int m = row0 + wm + mt * 16 + g * 4 + i;
        int n = col0 + wn + nt * 16 + lm;
        int which = (n >= 1536) ? 2 : (n >= 768 ? 1 : 0);
        int d = n - which * 768;
        int head = d >> 6, hd = d & 63;
        int b = m >> 10, nn = m & 1023;
        int bh = b * 12 + head;
        size_t addr = (which < 2)
            ? ((size_t)which * 3145728u + (size_t)bh * 65536u + (size_t)nn * 64 + hd)
            : (6291456u + (size_t)bh * 65536u + (size_t)hd * 1024 + nn);  // V^T
        qkvb[addr] = f2bf(acc[mt][nt][i]);
      }
}

// grid 768 (1D). XCD-swizzled: per XCD 6 bh. Double-buffered K/V; lP is
// wave-private so no barrier between P-write and P-read.
__global__ __launch_bounds__(256, 2) void k_attn(
    const unsigned short* __restrict__ qkv, unsigned short* __restrict__ abuf)
{
  __shared__ unsigned short lK[2][4096];
  __shared__ unsigned short lV[2][4096];     // V^T tile: [d][seq]
  __shared__ unsigned short lP[4][16 * 72];  // per-wave P, padded ld=72
  const int tid = threadIdx.x, lane = tid & 63, w = tid >> 6;
  const int g = lane >> 4, lm = lane & 15;
  const int f = blockIdx.x, xcd = f & 7, s = f >> 3;
  const int bh = xcd * 6 + (s >> 4);
  const int qt = s & 15;
  const unsigned short* qsec = qkv + (size_t)bh * 65536u;
  const unsigned short* ksec = qkv + 3145728u + (size_t)bh * 65536u;
  const unsigned short* vsec = qkv + 6291456u + (size_t)bh * 65536u;

  s16x8 bq[2];
  {
    const unsigned short* qp = qsec + (size_t)(qt * 64 + w * 16 + lm) * 64 + g * 8;
    bq[0] = *(const s16x8*)(qp);
    bq[1] = *(const s16x8*)(qp + 32);
  }
  f32x4 oacc[4];
#pragma unroll
  for (int dt = 0; dt < 4; ++dt) { oacc[dt][0]=0.f; oacc[dt][1]=0.f; oacc[dt][2]=0.f; oacc[dt][3]=0.f; }
  float m_i = -3.0e38f, l_i = 0.f;

  auto stage = [&](int kt, int p) {
#pragma unroll
    for (int it = 0; it < 2; ++it) {
      int c = (w * 2 + it) * 64 + lane;
      int r = c >> 3, sl = (c & 7) ^ (r & 7);
      async_cp16(ksec + (size_t)(kt * 64 + r) * 64 + sl * 8, lK[p] + (w * 2 + it) * 512);
      async_cp16(vsec + (size_t)r * 1024 + kt * 64 + sl * 8, lV[p] + (w * 2 + it) * 512);
    }
  };
  stage(0, 0);
  int p = 0;
  for (int kt = 0; kt < 16; ++kt) {
    __syncthreads();                       // KV buf p staged
    if (kt < 15) stage(kt + 1, p ^ 1);
    f32x4 st[4];
#pragma unroll
    for (int mt = 0; mt < 4; ++mt) {
      f32x4 z; z[0]=0.f; z[1]=0.f; z[2]=0.f; z[3]=0.f;
#pragma unroll
      for (int ks = 0; ks < 2; ++ks) {
        int ra = mt * 16 + lm;
        s16x8 a = *(const s16x8*)(lK[p] + ra * 64 + (((ks * 4 + g) ^ (ra & 7)) << 3));
        z = __builtin_amdgcn_mfma_f32_16x16x32_bf16(a, bq[ks], z, 0, 0, 0);
      }
      st[mt] = z;   // S^T[kcol = mt*16 + g*4 + i][qrow = lm]
    }
    float mx = -3.0e38f;
#pragma unroll
    for (int mt = 0; mt < 4; ++mt) {
      st[mt] *= 0.125f;
#pragma unroll
      for (int i = 0; i < 4; ++i) mx = fmaxf(mx, st[mt][i]);
    }
    mx = fmaxf(mx, __shfl_xor(mx, 16, 64));
    mx = fmaxf(mx, __shfl_xor(mx, 32, 64));
    float mnew = fmaxf(m_i, mx);
    float alpha = expf(m_i - mnew);
    float psum = 0.f;
#pragma unroll
    for (int mt = 0; mt < 4; ++mt) {
      u16x4 pk;
#pragma unroll
      for (int i = 0; i < 4; ++i) {
        float p2 = expf(st[mt][i] - mnew);
        psum += p2;
        pk[i] = f2bf(p2);
      }
      *(u16x4*)(&lP[w][lm * 72 + mt * 16 + g * 4]) = pk;
    }
    psum += __shfl_xor(psum, 16, 64);
    psum += __shfl_xor(psum, 32, 64);
    l_i = l_i * alpha + psum;
    m_i = mnew;
    float al[4];
#pragma unroll
    for (int i = 0; i < 4; ++i) al[i] = __shfl(alpha, (lane & 48) | (g * 4 + i), 64);
#pragma unroll
    for (int dt = 0; dt < 4; ++dt) {
#pragma unroll
      for (int i = 0; i < 4; ++i) oacc[dt][i] *= al[i];
    }
#pragma unroll
    for (int ks = 0; ks < 2; ++ks) {
      s16x8 ap = *(const s16x8*)(&lP[w][lm * 72 + ks * 32 + g * 8]);
#pragma unroll
      for (int dt = 0; dt < 4; ++dt) {
        int rv = dt * 16 + lm;
        s16x8 bv = *(const s16x8*)(lV[p] + rv * 64 + (((ks * 4 + g) ^ (rv & 7)) << 3));
        oacc[dt] = __builtin_amdgcn_mfma_f32_16x16x32_bf16(ap, bv, oacc[dt], 0, 0, 0);
      }
    }
    p ^= 1;
  }
  float linv[4];
#pragma unroll
  for (int i = 0; i < 4; ++i)
    linv[i] = 1.f / __shfl(l_i, (lane & 48) | (g * 4 + i), 64);
  int b = bh / 12, head = bh % 12;
#pragma unroll
  for (int dt = 0; dt < 4; ++dt)
#pragma unroll
    for (int i = 0; i < 4; ++i) {
      int q = qt * 64 + w * 16 + g * 4 + i;
      int col = head * 64 + dt * 16 + lm;
      abuf[(size_t)(b * 1024 + q) * DIM_ + col] = f2bf(oacc[dt][i] * linv[i]);
    }
}

__global__ __launch_bounds__(256, 4) void k_proj(
    const unsigned short* __restrict__ abuf, const void* __restrict__ projw,
    const float* __restrict__ projb, const float* __restrict__ x,
    float* __restrict__ x1)
{
  GEMM_PROLOGUE
  int row0 = blockIdx.x * 128, col0 = blockIdx.y * 128;
  A_PTRS(abuf, DIM_)
  gemm_loop<true>(aS[0], aS[1], projw, DIM_, 0, DIM_, col0, lA, lB, acc);
#pragma unroll
  for (int mt = 0; mt < 4; ++mt)
#pragma unroll
    for (int nt = 0; nt < 4; ++nt)
#pragma unroll
      for (int i = 0; i < 4; ++i) {
        int m = row0 + wm + mt * 16 + g * 4 + i;
        int n = col0 + wn + nt * 16 + lm;
        size_t idx = (size_t)m * DIM_ + n;
        x1[idx] = acc[mt][nt][i] + projb[n] + x[idx];
      }
}

// grid 1728 (1D). Per XCD 9 row-tiles, cols fastest in groups of 8.
// A staged straight from h2 via tok_of indirection.
template<bool BBF>
__global__ __launch_bounds__(256, 4) void k_ffn1(
    const unsigned short* __restrict__ h2, const void* __restrict__ w1,
    const float* __restrict__ b1, const int* __restrict__ off,
    const int* __restrict__ tok_of, const unsigned short* __restrict__ zrow,
    unsigned short* __restrict__ hidden)
{
  int f = blockIdx.x, xcd = f & 7, s = f >> 3;
  int cg = s / 72, rr = (s % 72) >> 3, c = cg * 8 + (s & 7);
  int row0 = (xcd * 9 + rr) * 128, col0 = c * 128;
  if (row0 >= off[8]) return;
  int e = 0;
  while (!(row0 >= off[e] && row0 < off[e + 1])) ++e;
  GEMM_PROLOGUE
  const unsigned short* aS[2];
#pragma unroll
  for (int it = 0; it < 2; ++it) {
    int cc = (w * 2 + it) * 64 + lane;
    int r = cc >> 2, ks = ((cc & 3) ^ ((r >> 1) & 3)) << 3;
    int tk = tok_of[row0 + r];
    const unsigned short* rp = (tk >= 0) ? (h2 + (size_t)tk * DIM_) : zrow;
    aS[it] = rp + ks;
  }
  const char* Bp = (const char*)w1 + (size_t)e * HID_ * DIM_ * (BBF ? 2 : 4);
  gemm_loop<BBF>(aS[0], aS[1], Bp, DIM_, 0, DIM_, col0, lA, lB, acc);
#pragma unroll
  for (int mt = 0; mt < 4; ++mt)
#pragma unroll
    for (int nt = 0; nt < 4; ++nt)
#pragma unroll
      for (int i = 0; i < 4; ++i) {
        int m = row0 + wm + mt * 16 + g * 4 + i;
        int n = col0 + wn + nt * 16 + lm;
        float v = acc[mt][nt][i] + b1[e * HID_ + n];
        float ge = 0.5f * v * (1.f + erff(v * 0.70710678118654752f));
        hidden[(size_t)m * HID_ + n] = f2bf(ge);
      }
}

// grid 864 (1D): 72 row x 6 col x 2 K-halves (split-K). Epilogue: fp32
// atomicAdd of cw*(ye+b2) straight into out (pre-initialized to x1 by
// k_ln2gate) -- no partial buffers, no combine pass.
template<bool BBF>
__global__ __launch_bounds__(256, 4) void k_ffn2(
    const unsigned short* __restrict__ hidden, const void* __restrict__ w2,
    const float* __restrict__ b2, const int* __restrict__ off,
    const int* __restrict__ tok_of, const float* __restrict__ cw_of,
    float* __restrict__ out)
{
  int f = blockIdx.x, xcd = f & 7, s = f >> 3;
  int cg = s / 54, rem = s % 54;
  int rr = rem / 6, kk = (rem % 6) / 3, c = cg * 3 + rem % 3;
  int row0 = (xcd * 9 + rr) * 128, col0 = c * 128;
  if (row0 >= off[8]) return;
  int e = 0;
  while (!(row0 >= off[e] && row0 < off[e + 1])) ++e;
  GEMM_PROLOGUE
  A_PTRS(hidden, HID_)
  const char* Bp = (const char*)w2 + (size_t)e * DIM_ * HID_ * (BBF ? 2 : 4);
  gemm_loop<BBF>(aS[0], aS[1], Bp, HID_, kk * 1536, kk * 1536 + 1536, col0, lA, lB, acc);
#pragma unroll
  for (int mt = 0; mt < 4; ++mt)
#pragma unroll
    for (int i = 0; i < 4; ++i) {
      int m = row0 + wm + mt * 16 + g * 4 + i;
      int tok = tok_of[m];
      if (tok < 0) continue;
      float cw = cw_of[m];
      float* orow = out + (size_t)tok * DIM_;
#pragma unroll
      for (int nt = 0; nt < 4; ++nt) {
        int n = col0 + wn + nt * 16 + lm;
        float v = acc[mt][nt][i] + (kk ? 0.f : b2[e * DIM_ + n]);
        atomicAdd(orow + n, cw * v);
      }
    }
}

__global__ __launch_bounds__(256) void k_ln2gate(
    const float* __restrict__ x1, const float* __restrict__ gg,
    const float* __restrict__ bb, const float* __restrict__ gw,
    const float* __restrict__ gb, unsigned short* __restrict__ h2,
    int* __restrict__ topidx, float* __restrict__ tops, float* __restrict__ out)
{
  int t = blockIdx.x, tid = threadIdx.x;
  const float* xr = x1 + (size_t)t * DIM_;
  float v0 = xr[tid], v1 = xr[tid + 256], v2 = xr[tid + 512];
  // pre-seed out with the residual x1 (ffn2 atomically accumulates onto it)
  float* orow = out + (size_t)t * DIM_;
  orow[tid] = v0; orow[tid + 256] = v1; orow[tid + 512] = v2;
  float s = v0 + v1 + v2, q = v0 * v0 + v1 * v1 + v2 * v2;
  for (int o = 32; o; o >>= 1) { s += __shfl_xor(s, o, 64); q += __shfl_xor(q, o, 64); }
  __shared__ float red[8];
  __shared__ float part[32];
  int lane = tid & 63, w = tid >> 6;
  if (!lane) { red[w] = s; red[4 + w] = q; }
  __syncthreads();
  s = red[0] + red[1] + red[2] + red[3];
  q = red[4] + red[5] + red[6] + red[7];
  float mean = s * (1.f / 768.f);
  float rstd = rsqrtf(q * (1.f / 768.f) - mean * mean + 1e-5f);
  float y0 = (v0 - mean) * rstd * gg[tid]       + bb[tid];
  float y1 = (v1 - mean) * rstd * gg[tid + 256] + bb[tid + 256];
  float y2 = (v2 - mean) * rstd * gg[tid + 512] + bb[tid + 512];
  unsigned short* hrow = h2 + (size_t)t * DIM_;
  hrow[tid] = f2bf(y0); hrow[tid + 256] = f2bf(y1); hrow[tid + 512] = f2bf(y2);
#pragma unroll
  for (int e = 0; e < 8; ++e) {
    float p = y0 * gw[e * DIM_ + tid] + y1 * gw[e * DIM_ + tid + 256] + y2 * gw[e * DIM_ + tid + 512];
    for (int o = 32; o; o >>= 1) p += __shfl_xor(p, o, 64);
    if (!lane) part[e * 4 + w] = p;
  }
  __syncthreads();
  if (tid == 0) {
    float lg[8];
#pragma unroll
    for (int e = 0; e < 8; ++e)
      lg[e] = part[e * 4] + part[e * 4 + 1] + part[e * 4 + 2] + part[e * 4 + 3] + gb[e];
    int i0 = 0; float b0 = lg[0];
#pragma unroll
    for (int e = 1; e < 8; ++e) if (lg[e] > b0) { b0 = lg[e]; i0 = e; }
    int i1 = (i0 == 0) ? 1 : 0; float b1v = lg[i1];
#pragma unroll
    for (int e = 0; e < 8; ++e)
      if (e != i0 && lg[e] > b1v) { b1v = lg[e]; i1 = e; }
    float e1 = expf(b1v - b0);
    float s0 = 1.f / (1.f + e1);
    topidx[t * 2] = i0; topidx[t * 2 + 1] = i1;
    tops[t * 2] = s0;  tops[t * 2 + 1] = e1 / (1.f + e1);
  }
}

// single block: counts -> padded offsets -> tok/cw maps + zero row
__global__ __launch_bounds__(1024) void k_route(
    const int* __restrict__ topidx, const float* __restrict__ tops,
    int* __restrict__ off, int* __restrict__ tok_of, float* __restrict__ cw_of,
    unsigned short* __restrict__ zrow)
{
  __shared__ int scnt[8], soff[9], sfill[8];
  int tid = threadIdx.x;
  if (tid < 8) { scnt[tid] = 0; sfill[tid] = 0; }
  if (tid < 384) ((unsigned*)zrow)[tid] = 0;
  for (int j = tid; j < CAP; j += 1024) tok_of[j] = -1;
  __syncthreads();
#pragma unroll
  for (int j = 0; j < 8; ++j)
    atomicAdd(&scnt[topidx[tid + j * 1024]], 1);
  __syncthreads();
  if (tid == 0) {
    int a = 0;
    for (int e = 0; e < 8; ++e) { soff[e] = a; off[e] = a; a += (scnt[e] + 127) & ~127; }
    soff[8] = a; off[8] = a;
  }
  __syncthreads();
#pragma unroll
  for (int j = 0; j < 8; ++j) {
    int i = tid + j * 1024;
    int e = topidx[i];
    int p = soff[e] + atomicAdd(&sfill[e], 1);
    tok_of[p] = i >> 1;
    cw_of[p] = tops[i];
  }
}

extern "C" void kernel_launch(void* const* d_in, const int* in_sizes, int n_in,
                              void* d_out, int out_size, void* d_ws, size_t ws_size,
                              hipStream_t stream) {
  const float* x     = (const float*)d_in[0];
  const float* ln1g  = (const float*)d_in[1];
  const float* ln1b  = (const float*)d_in[2];
  const float* qkvw  = (const float*)d_in[3];
  const float* projw = (const float*)d_in[4];
  const float* projb = (const float*)d_in[5];
  const float* ln2g  = (const float*)d_in[6];
  const float* ln2b  = (const float*)d_in[7];
  const float* gw    = (const float*)d_in[8];
  const float* gb    = (const float*)d_in[9];
  const float* w1    = (const float*)d_in[10];
  const float* b1    = (const float*)d_in[11];
  const float* w2    = (const float*)d_in[12];
  const float* b2    = (const float*)d_in[13];
  float* out = (float*)d_out;

  char* base = (char*)d_ws;
  unsigned short* hbf    = (unsigned short*)(base + 0);          // 6.29MB (reused as h2)
  unsigned short* qkvb   = (unsigned short*)(base + 6291456);    // 18.9MB
  unsigned short* abuf   = (unsigned short*)(base + 25165824);   // 6.29MB (reused as routing scratch)
  float*          x1     = (float*)(base + 31457280);            // 12.6MB
  unsigned short* hidden = (unsigned short*)(base + 44040192);   // 56.6MB
  // 100663296..128974848 free (old ye bufs)

  const size_t FULL_NEED = 209190912;   // + bf16 weight copies
  const bool full = ws_size >= FULL_NEED;
  unsigned short *wqkvbf, *wprojbf, *w1bf = nullptr, *w2bf = nullptr;
  if (full) {
    wqkvbf  = (unsigned short*)(base + 128974848);
    wprojbf = (unsigned short*)(base + 132513792);
    w1bf    = (unsigned short*)(base + 133693440);
    w2bf    = (unsigned short*)(base + 171442176);
  } else {
    wqkvbf  = (unsigned short*)(base + 44040192);     // hidden region, free pre-ffn
    wprojbf = (unsigned short*)(base + 44040192 + 3538944);
  }
  // routing scratch lives in abuf's region (abuf dead after k_proj)
  char* small = base + 25165824;
  int*   topidx = (int*)small;                        // 32KB
  float* tops   = (float*)(small + 32768);            // 32KB
  int*   off    = (int*)(small + 65536);              // 64B
  int*   tok_of = (int*)(small + 65600);              // 36.9KB
  float* cw_of  = (float*)(small + 102464);           // 36.9KB
  unsigned short* zrow = (unsigned short*)(small + 139392);  // 1.5KB zeros
  unsigned short* h2 = hbf;

  k_cvtln<<<1152 + NTOK, 256, 0, stream>>>(qkvw, projw, wqkvbf, wprojbf,
                                           x, ln1g, ln1b, hbf);
  if (full)
    k_qkvcvt<true><<<576 + 18432, 256, 0, stream>>>(hbf, wqkvbf, qkvb,
                                                    w1, w2, w1bf, w2bf);
  else
    k_qkvcvt<false><<<576, 256, 0, stream>>>(hbf, wqkvbf, qkvb,
                                             nullptr, nullptr, nullptr, nullptr);
  k_attn<<<768, 256, 0, stream>>>(qkvb, abuf);
  k_proj<<<dim3(32, 6), 256, 0, stream>>>(abuf, wprojbf, projb, x, x1);
  k_ln2gate<<<NTOK, 256, 0, stream>>>(x1, ln2g, ln2b, gw, gb, h2, topidx, tops, out);
  k_route<<<1, 1024, 0, stream>>>(topidx, tops, off, tok_of, cw_of, zrow);
  if (full) {
    k_ffn1<true><<<1728, 256, 0, stream>>>(h2, w1bf, b1, off, tok_of, zrow, hidden);
    k_ffn2<true><<<864, 256, 0, stream>>>(hidden, w2bf, b2, off, tok_of, cw_of, out);
  } else {
    k_ffn1<false><<<1728, 256, 0, stream>>>(h2, w1, b1, off, tok_of, zrow, hidden);
    k_ffn2<false><<<864, 256, 0, stream>>>(hidden, w2, b2, off, tok_of, cw_of, out);
  }
}

// Round 8
// 477.677 us; speedup vs baseline: 1.0534x; 1.0534x over previous
//
#include <hip/hip_runtime.h>
#include <math.h>

typedef short s16x8 __attribute__((ext_vector_type(8)));
typedef float f32x4 __attribute__((ext_vector_type(4)));
typedef unsigned short u16x4 __attribute__((ext_vector_type(4)));
typedef unsigned short u16x8 __attribute__((ext_vector_type(8)));

#define DIM_ 768
#define HID_ 3072
#define NTOK 4096
#define CAP 9216

__device__ __forceinline__ unsigned short f2bf(float f) {
  unsigned u = __float_as_uint(f);
  u += 0x7fffu + ((u >> 16) & 1u);   // RNE
  return (unsigned short)(u >> 16);
}
__device__ __forceinline__ float bf2f(unsigned short u) {
  return __uint_as_float(((unsigned)u) << 16);
}

__device__ __forceinline__ void async_cp16(const void* g, void* l) {
  __builtin_amdgcn_global_load_lds(
      (const __attribute__((address_space(1))) void*)g,
      (__attribute__((address_space(3))) void*)l, 16, 0, 0);
}

__device__ __forceinline__ void cvt2048(const float* __restrict__ s,
                                        unsigned short* __restrict__ d, long i) {
  float4 a = *(const float4*)(s + i);
  float4 b = *(const float4*)(s + i + 4);
  u16x8 o;
  o[0]=f2bf(a.x); o[1]=f2bf(a.y); o[2]=f2bf(a.z); o[3]=f2bf(a.w);
  o[4]=f2bf(b.x); o[5]=f2bf(b.y); o[6]=f2bf(b.z); o[7]=f2bf(b.w);
  *(u16x8*)(d + i) = o;
}

// ---------------- 128x128 bf16 MFMA GEMM mainloop (R3 structure, proven) --
template<bool BBF>
__device__ __forceinline__ void gemm_loop(
    const unsigned short* aS0, const unsigned short* aS1,
    const void* __restrict__ Bv, int ldb,
    int kbeg, int kend, int col0,
    unsigned short* lA, unsigned short* lB,   // each 2*4096 elements
    f32x4 acc[4][4])
{
  const int tid = threadIdx.x;
  const int lane = tid & 63;
  const int w = tid >> 6;
  const int wm = (w >> 1) << 6;
  const int wn = (w & 1) << 6;
  const int g = lane >> 4;
  const int lm = lane & 15;

  if constexpr (BBF) {
    const unsigned short* Bb = (const unsigned short*)Bv;
    const unsigned short* bS[2];
#pragma unroll
    for (int it = 0; it < 2; ++it) {
      int c = (w * 2 + it) * 64 + lane;
      int r = c >> 2, ks = ((c & 3) ^ ((r >> 1) & 3)) << 3;
      bS[it] = Bb + (size_t)(col0 + r) * ldb + ks;
    }
    auto stage = [&](int k0, int p) {
      async_cp16(aS0 + k0, lA + p * 4096 + (w * 2 + 0) * 512);
      async_cp16(bS[0] + k0, lB + p * 4096 + (w * 2 + 0) * 512);
      async_cp16(aS1 + k0, lA + p * 4096 + (w * 2 + 1) * 512);
      async_cp16(bS[1] + k0, lB + p * 4096 + (w * 2 + 1) * 512);
    };
    stage(kbeg, 0);
    int p = 0;
    for (int k0 = kbeg; k0 < kend; k0 += 32) {
      __syncthreads();                       // buf p staged
      if (k0 + 32 < kend) stage(k0 + 32, p ^ 1);
      const unsigned short* bA = lA + p * 4096;
      const unsigned short* bB = lB + p * 4096;
      s16x8 a_frag[4], b_frag[4];
#pragma unroll
      for (int mt = 0; mt < 4; ++mt) {
        int ra = wm + mt * 16 + lm;
        a_frag[mt] = *(const s16x8*)(bA + ra * 32 + ((g ^ ((ra >> 1) & 3)) << 3));
      }
#pragma unroll
      for (int nt = 0; nt < 4; ++nt) {
        int cb = wn + nt * 16 + lm;
        b_frag[nt] = *(const s16x8*)(bB + cb * 32 + ((g ^ ((cb >> 1) & 3)) << 3));
      }
#pragma unroll
      for (int mt = 0; mt < 4; ++mt)
#pragma unroll
        for (int nt = 0; nt < 4; ++nt)
          acc[mt][nt] = __builtin_amdgcn_mfma_f32_16x16x32_bf16(
              a_frag[mt], b_frag[nt], acc[mt][nt], 0, 0, 0);
      p ^= 1;
    }
  } else {
    const float* Bf = (const float*)Bv;
    for (int k0 = kbeg; k0 < kend; k0 += 32) {
      __syncthreads();
      async_cp16(aS0 + k0, lA + (w * 2 + 0) * 512);
      async_cp16(aS1 + k0, lA + (w * 2 + 1) * 512);
#pragma unroll
      for (int it = 0; it < 4; ++it) {
        int f = it * 1024 + tid * 4;
        int br = f >> 5, ke = f & 31;
        const float4 vv = *(const float4*)(Bf + (size_t)(col0 + br) * ldb + (k0 + ke));
        u16x4 pk;
        pk[0] = f2bf(vv.x); pk[1] = f2bf(vv.y); pk[2] = f2bf(vv.z); pk[3] = f2bf(vv.w);
        int ksw = (((ke >> 3) ^ ((br >> 1) & 3)) << 3) + (ke & 7);
        *(u16x4*)(lB + br * 32 + ksw) = pk;
      }
      __syncthreads();
      s16x8 a_frag[4], b_frag[4];
#pragma unroll
      for (int mt = 0; mt < 4; ++mt) {
        int ra = wm + mt * 16 + lm;
        a_frag[mt] = *(const s16x8*)(lA + ra * 32 + ((g ^ ((ra >> 1) & 3)) << 3));
      }
#pragma unroll
      for (int nt = 0; nt < 4; ++nt) {
        int cb = wn + nt * 16 + lm;
        b_frag[nt] = *(const s16x8*)(lB + cb * 32 + ((g ^ ((cb >> 1) & 3)) << 3));
      }
#pragma unroll
      for (int mt = 0; mt < 4; ++mt)
#pragma unroll
        for (int nt = 0; nt < 4; ++nt)
          acc[mt][nt] = __builtin_amdgcn_mfma_f32_16x16x32_bf16(
              a_frag[mt], b_frag[nt], acc[mt][nt], 0, 0, 0);
    }
  }
}

#define GEMM_PROLOGUE                                   \
  __shared__ unsigned short lA[8192];                   \
  __shared__ unsigned short lB[8192];                   \
  f32x4 acc[4][4];                                      \
  _Pragma("unroll") for (int a_ = 0; a_ < 4; ++a_)      \
  _Pragma("unroll") for (int b_ = 0; b_ < 4; ++b_) {    \
    acc[a_][b_][0]=0.f; acc[a_][b_][1]=0.f;             \
    acc[a_][b_][2]=0.f; acc[a_][b_][3]=0.f; }           \
  const int lane = threadIdx.x & 63;                    \
  const int w = threadIdx.x >> 6;                       \
  const int wm = (w >> 1) << 6, wn = (w & 1) << 6;      \
  const int g = lane >> 4, lm = lane & 15;

#define A_PTRS(Abase, LDA)                                            \
  const unsigned short* aS[2];                                        \
  _Pragma("unroll") for (int it_ = 0; it_ < 2; ++it_) {               \
    int c_ = (w * 2 + it_) * 64 + lane;                               \
    int r_ = c_ >> 2, ks_ = ((c_ & 3) ^ ((r_ >> 1) & 3)) << 3;        \
    aS[it_] = (Abase) + (size_t)(row0 + r_) * (LDA) + ks_;            \
  }

// ---------------- kernels -------------------------------------------------

// fused: qkvw+projw convert (blocks < 1152) + LayerNorm1 (the rest).
__global__ void k_cvtln(const float* __restrict__ s0, const float* __restrict__ s1,
                        unsigned short* __restrict__ d0, unsigned short* __restrict__ d1,
                        const float* __restrict__ x, const float* __restrict__ gg,
                        const float* __restrict__ bb, unsigned short* __restrict__ outb)
{
  __shared__ float red[8];
  if ((int)blockIdx.x < 1152) {
    long i = (long)(blockIdx.x * 256 + threadIdx.x) * 8;
    if (i < 1769472) cvt2048(s0, d0, i);
    else             cvt2048(s1 - 1769472, d1 - 1769472, i);
    return;
  }
  int t = blockIdx.x - 1152, tid = threadIdx.x;
  const float* xr = x + (size_t)t * DIM_;
  float v0 = xr[tid], v1 = xr[tid + 256], v2 = xr[tid + 512];
  float s = v0 + v1 + v2, q = v0 * v0 + v1 * v1 + v2 * v2;
  for (int o = 32; o; o >>= 1) { s += __shfl_xor(s, o, 64); q += __shfl_xor(q, o, 64); }
  int lane = tid & 63, w = tid >> 6;
  if (!lane) { red[w] = s; red[4 + w] = q; }
  __syncthreads();
  s = red[0] + red[1] + red[2] + red[3];
  q = red[4] + red[5] + red[6] + red[7];
  float mean = s * (1.f / 768.f);
  float rstd = rsqrtf(q * (1.f / 768.f) - mean * mean + 1e-5f);
  unsigned short* orow = outb + (size_t)t * DIM_;
  orow[tid]       = f2bf((v0 - mean) * rstd * gg[tid]       + bb[tid]);
  orow[tid + 256] = f2bf((v1 - mean) * rstd * gg[tid + 256] + bb[tid + 256]);
  orow[tid + 512] = f2bf((v2 - mean) * rstd * gg[tid + 512] + bb[tid + 512]);
}

// blocks 0..575: qkv GEMM (XCD-swizzled). blocks 576+: w1/w2 fp32->bf16
// convert, co-resident with the GEMM (m114: co-scheduled pipes, time=max).
template<bool FULL>
__global__ __launch_bounds__(256, 4) void k_qkvcvt(
    const unsigned short* __restrict__ hbf, const void* __restrict__ qkvw,
    unsigned short* __restrict__ qkvb,
    const float* __restrict__ w1f, const float* __restrict__ w2f,
    unsigned short* __restrict__ w1bf, unsigned short* __restrict__ w2bf)
{
  GEMM_PROLOGUE
  if constexpr (FULL) {
    if ((int)blockIdx.x >= 576) {
      int c2 = blockIdx.x - 576;
      if (c2 < 9216) cvt2048(w1f, w1bf, (long)c2 * 2048 + threadIdx.x * 8);
      else           cvt2048(w2f, w2bf, (long)(c2 - 9216) * 2048 + threadIdx.x * 8);
      return;
    }
  }
  int f = blockIdx.x, xcd = f & 7, s = f >> 3;
  int cg = s / 24, rr = (s % 24) / 6, c = cg * 6 + s % 6;
  int row0 = (xcd * 4 + rr) * 128, col0 = c * 128;
  A_PTRS(hbf, DIM_)
  gemm_loop<true>(aS[0], aS[1], qkvw, DIM_, 0, DIM_, col0, lA, lB, acc);
#pragma unroll
  for (int mt = 0; mt < 4; ++mt)
#pragma unroll
    for (int nt = 0; nt < 4; ++nt)
#pragma unroll
      for (int i = 0; i < 4; ++i) {
        int m = row0 + wm + mt * 16 + g * 4 + i;
        int n = col0 + wn + nt * 16 + lm;
        int which = (n >= 1536) ? 2 : (n >= 768 ? 1 : 0);
        int d = n - which * 768;
        int head = d >> 6, hd = d & 63;
        int b = m >> 10, nn = m & 1023;
        int bh = b * 12 + head;
        size_t addr = (which < 2)
            ? ((size_t)which * 3145728u + (size_t)bh * 65536u + (size_t)nn * 64 + hd)
            : (6291456u + (size_t)bh * 65536u + (size_t)hd * 1024 + nn);  // V^T
        qkvb[addr] = f2bf(acc[mt][nt][i]);
      }
}

// grid 768 (1D). XCD-swizzled: per XCD 6 bh. Double-buffered K/V; lP is
// wave-private so no barrier between P-write and P-read.
__global__ __launch_bounds__(256, 2) void k_attn(
    const unsigned short* __restrict__ qkv, unsigned short* __restrict__ abuf)
{
  __shared__ unsigned short lK[2][4096];
  __shared__ unsigned short lV[2][4096];     // V^T tile: [d][seq]
  __shared__ unsigned short lP[4][16 * 72];  // per-wave P, padded ld=72
  const int tid = threadIdx.x, lane = tid & 63, w = tid >> 6;
  const int g = lane >> 4, lm = lane & 15;
  const int f = blockIdx.x, xcd = f & 7, s = f >> 3;
  const int bh = xcd * 6 + (s >> 4);
  const int qt = s & 15;
  const unsigned short* qsec = qkv + (size_t)bh * 65536u;
  const unsigned short* ksec = qkv + 3145728u + (size_t)bh * 65536u;
  const unsigned short* vsec = qkv + 6291456u + (size_t)bh * 65536u;

  s16x8 bq[2];
  {
    const unsigned short* qp = qsec + (size_t)(qt * 64 + w * 16 + lm) * 64 + g * 8;
    bq[0] = *(const s16x8*)(qp);
    bq[1] = *(const s16x8*)(qp + 32);
  }
  f32x4 oacc[4];
#pragma unroll
  for (int dt = 0; dt < 4; ++dt) { oacc[dt][0]=0.f; oacc[dt][1]=0.f; oacc[dt][2]=0.f; oacc[dt][3]=0.f; }
  float m_i = -3.0e38f, l_i = 0.f;

  auto stage = [&](int kt, int p) {
#pragma unroll
    for (int it = 0; it < 2; ++it) {
      int c = (w * 2 + it) * 64 + lane;
      int r = c >> 3, sl = (c & 7) ^ (r & 7);
      async_cp16(ksec + (size_t)(kt * 64 + r) * 64 + sl * 8, lK[p] + (w * 2 + it) * 512);
      async_cp16(vsec + (size_t)r * 1024 + kt * 64 + sl * 8, lV[p] + (w * 2 + it) * 512);
    }
  };
  stage(0, 0);
  int p = 0;
  for (int kt = 0; kt < 16; ++kt) {
    __syncthreads();                       // KV buf p staged
    if (kt < 15) stage(kt + 1, p ^ 1);
    f32x4 st[4];
#pragma unroll
    for (int mt = 0; mt < 4; ++mt) {
      f32x4 z; z[0]=0.f; z[1]=0.f; z[2]=0.f; z[3]=0.f;
#pragma unroll
      for (int ks = 0; ks < 2; ++ks) {
        int ra = mt * 16 + lm;
        s16x8 a = *(const s16x8*)(lK[p] + ra * 64 + (((ks * 4 + g) ^ (ra & 7)) << 3));
        z = __builtin_amdgcn_mfma_f32_16x16x32_bf16(a, bq[ks], z, 0, 0, 0);
      }
      st[mt] = z;   // S^T[kcol = mt*16 + g*4 + i][qrow = lm]
    }
    float mx = -3.0e38f;
#pragma unroll
    for (int mt = 0; mt < 4; ++mt) {
      st[mt] *= 0.125f;
#pragma unroll
      for (int i = 0; i < 4; ++i) mx = fmaxf(mx, st[mt][i]);
    }
    mx = fmaxf(mx, __shfl_xor(mx, 16, 64));
    mx = fmaxf(mx, __shfl_xor(mx, 32, 64));
    float mnew = fmaxf(m_i, mx);
    float alpha = expf(m_i - mnew);
    float psum = 0.f;
#pragma unroll
    for (int mt = 0; mt < 4; ++mt) {
      u16x4 pk;
#pragma unroll
      for (int i = 0; i < 4; ++i) {
        float p2 = expf(st[mt][i] - mnew);
        psum += p2;
        pk[i] = f2bf(p2);
      }
      *(u16x4*)(&lP[w][lm * 72 + mt * 16 + g * 4]) = pk;
    }
    psum += __shfl_xor(psum, 16, 64);
    psum += __shfl_xor(psum, 32, 64);
    l_i = l_i * alpha + psum;
    m_i = mnew;
    float al[4];
#pragma unroll
    for (int i = 0; i < 4; ++i) al[i] = __shfl(alpha, (lane & 48) | (g * 4 + i), 64);
#pragma unroll
    for (int dt = 0; dt < 4; ++dt) {
#pragma unroll
      for (int i = 0; i < 4; ++i) oacc[dt][i] *= al[i];
    }
#pragma unroll
    for (int ks = 0; ks < 2; ++ks) {
      s16x8 ap = *(const s16x8*)(&lP[w][lm * 72 + ks * 32 + g * 8]);
#pragma unroll
      for (int dt = 0; dt < 4; ++dt) {
        int rv = dt * 16 + lm;
        s16x8 bv = *(const s16x8*)(lV[p] + rv * 64 + (((ks * 4 + g) ^ (rv & 7)) << 3));
        oacc[dt] = __builtin_amdgcn_mfma_f32_16x16x32_bf16(ap, bv, oacc[dt], 0, 0, 0);
      }
    }
    p ^= 1;
  }
  float linv[4];
#pragma unroll
  for (int i = 0; i < 4; ++i)
    linv[i] = 1.f / __shfl(l_i, (lane & 48) | (g * 4 + i), 64);
  int b = bh / 12, head = bh % 12;
#pragma unroll
  for (int dt = 0; dt < 4; ++dt)
#pragma unroll
    for (int i = 0; i < 4; ++i) {
      int q = qt * 64 + w * 16 + g * 4 + i;
      int col = head * 64 + dt * 16 + lm;
      abuf[(size_t)(b * 1024 + q) * DIM_ + col] = f2bf(oacc[dt][i] * linv[i]);
    }
}

__global__ __launch_bounds__(256, 4) void k_proj(
    const unsigned short* __restrict__ abuf, const void* __restrict__ projw,
    const float* __restrict__ projb, const float* __restrict__ x,
    float* __restrict__ x1)
{
  GEMM_PROLOGUE
  int row0 = blockIdx.x * 128, col0 = blockIdx.y * 128;
  A_PTRS(abuf, DIM_)
  gemm_loop<true>(aS[0], aS[1], projw, DIM_, 0, DIM_, col0, lA, lB, acc);
#pragma unroll
  for (int mt = 0; mt < 4; ++mt)
#pragma unroll
    for (int nt = 0; nt < 4; ++nt)
#pragma unroll
      for (int i = 0; i < 4; ++i) {
        int m = row0 + wm + mt * 16 + g * 4 + i;
        int n = col0 + wn + nt * 16 + lm;
        size_t idx = (size_t)m * DIM_ + n;
        x1[idx] = acc[mt][nt][i] + projb[n] + x[idx];
      }
}

// grid 1728 (1D). Per XCD 9 row-tiles, cols fastest in groups of 8.
// A staged straight from h2 via tok_of indirection.
template<bool BBF>
__global__ __launch_bounds__(256, 4) void k_ffn1(
    const unsigned short* __restrict__ h2, const void* __restrict__ w1,
    const float* __restrict__ b1, const int* __restrict__ off,
    const int* __restrict__ tok_of, const unsigned short* __restrict__ zrow,
    unsigned short* __restrict__ hidden)
{
  int f = blockIdx.x, xcd = f & 7, s = f >> 3;
  int cg = s / 72, rr = (s % 72) >> 3, c = cg * 8 + (s & 7);
  int row0 = (xcd * 9 + rr) * 128, col0 = c * 128;
  if (row0 >= off[8]) return;
  int e = 0;
  while (!(row0 >= off[e] && row0 < off[e + 1])) ++e;
  GEMM_PROLOGUE
  const unsigned short* aS[2];
#pragma unroll
  for (int it = 0; it < 2; ++it) {
    int cc = (w * 2 + it) * 64 + lane;
    int r = cc >> 2, ks = ((cc & 3) ^ ((r >> 1) & 3)) << 3;
    int tk = tok_of[row0 + r];
    const unsigned short* rp = (tk >= 0) ? (h2 + (size_t)tk * DIM_) : zrow;
    aS[it] = rp + ks;
  }
  const char* Bp = (const char*)w1 + (size_t)e * HID_ * DIM_ * (BBF ? 2 : 4);
  gemm_loop<BBF>(aS[0], aS[1], Bp, DIM_, 0, DIM_, col0, lA, lB, acc);
#pragma unroll
  for (int mt = 0; mt < 4; ++mt)
#pragma unroll
    for (int nt = 0; nt < 4; ++nt)
#pragma unroll
      for (int i = 0; i < 4; ++i) {
        int m = row0 + wm + mt * 16 + g * 4 + i;
        int n = col0 + wn + nt * 16 + lm;
        float v = acc[mt][nt][i] + b1[e * HID_ + n];
        float ge = 0.5f * v * (1.f + erff(v * 0.70710678118654752f));
        hidden[(size_t)m * HID_ + n] = f2bf(ge);
      }
}

// grid 864 (1D): 72 row x 6 col x 2 K-halves (split-K). Partials in bf16
// (R6 proven form -- fp32 atomics to out regressed 2x in R7, cross-XCD RMW).
template<bool BBF>
__global__ __launch_bounds__(256, 4) void k_ffn2(
    const unsigned short* __restrict__ hidden, const void* __restrict__ w2,
    const float* __restrict__ b2, const int* __restrict__ off,
    unsigned short* __restrict__ ye0, unsigned short* __restrict__ ye1)
{
  int f = blockIdx.x, xcd = f & 7, s = f >> 3;
  int cg = s / 54, rem = s % 54;
  int rr = rem / 6, kk = (rem % 6) / 3, c = cg * 3 + rem % 3;
  int row0 = (xcd * 9 + rr) * 128, col0 = c * 128;
  if (row0 >= off[8]) return;
  int e = 0;
  while (!(row0 >= off[e] && row0 < off[e + 1])) ++e;
  GEMM_PROLOGUE
  A_PTRS(hidden, HID_)
  const char* Bp = (const char*)w2 + (size_t)e * DIM_ * HID_ * (BBF ? 2 : 4);
  gemm_loop<BBF>(aS[0], aS[1], Bp, HID_, kk * 1536, kk * 1536 + 1536, col0, lA, lB, acc);
  unsigned short* yh = kk ? ye1 : ye0;
#pragma unroll
  for (int mt = 0; mt < 4; ++mt)
#pragma unroll
    for (int nt = 0; nt < 4; ++nt)
#pragma unroll
      for (int i = 0; i < 4; ++i) {
        int m = row0 + wm + mt * 16 + g * 4 + i;
        int n = col0 + wn + nt * 16 + lm;
        float v = acc[mt][nt][i] + (kk ? 0.f : b2[e * DIM_ + n]);
        yh[(size_t)m * DIM_ + n] = f2bf(v);
      }
}

__global__ __launch_bounds__(256) void k_ln2gate(
    const float* __restrict__ x1, const float* __restrict__ gg,
    const float* __restrict__ bb, const float* __restrict__ gw,
    const float* __restrict__ gb, unsigned short* __restrict__ h2,
    int* __restrict__ topidx, float* __restrict__ tops)
{
  int t = blockIdx.x, tid = threadIdx.x;
  const float* xr = x1 + (size_t)t * DIM_;
  float v0 = xr[tid], v1 = xr[tid + 256], v2 = xr[tid + 512];
  float s = v0 + v1 + v2, q = v0 * v0 + v1 * v1 + v2 * v2;
  for (int o = 32; o; o >>= 1) { s += __shfl_xor(s, o, 64); q += __shfl_xor(q, o, 64); }
  __shared__ float red[8];
  __shared__ float part[32];
  int lane = tid & 63, w = tid >> 6;
  if (!lane) { red[w] = s; red[4 + w] = q; }
  __syncthreads();
  s = red[0] + red[1] + red[2] + red[3];
  q = red[4] + red[5] + red[6] + red[7];
  float mean = s * (1.f / 768.f);
  float rstd = rsqrtf(q * (1.f / 768.f) - mean * mean + 1e-5f);
  float y0 = (v0 - mean) * rstd * gg[tid]       + bb[tid];
  float y1 = (v1 - mean) * rstd * gg[tid + 256] + bb[tid + 256];
  float y2 = (v2 - mean) * rstd * gg[tid + 512] + bb[tid + 512];
  unsigned short* hrow = h2 + (size_t)t * DIM_;
  hrow[tid] = f2bf(y0); hrow[tid + 256] = f2bf(y1); hrow[tid + 512] = f2bf(y2);
#pragma unroll
  for (int e = 0; e < 8; ++e) {
    float p = y0 * gw[e * DIM_ + tid] + y1 * gw[e * DIM_ + tid + 256] + y2 * gw[e * DIM_ + tid + 512];
    for (int o = 32; o; o >>= 1) p += __shfl_xor(p, o, 64);
    if (!lane) part[e * 4 + w] = p;
  }
  __syncthreads();
  if (tid == 0) {
    float lg[8];
#pragma unroll
    for (int e = 0; e < 8; ++e)
      lg[e] = part[e * 4] + part[e * 4 + 1] + part[e * 4 + 2] + part[e * 4 + 3] + gb[e];
    int i0 = 0; float b0 = lg[0];
#pragma unroll
    for (int e = 1; e < 8; ++e) if (lg[e] > b0) { b0 = lg[e]; i0 = e; }
    int i1 = (i0 == 0) ? 1 : 0; float b1v = lg[i1];
#pragma unroll
    for (int e = 0; e < 8; ++e)
      if (e != i0 && lg[e] > b1v) { b1v = lg[e]; i1 = e; }
    float e1 = expf(b1v - b0);
    float s0 = 1.f / (1.f + e1);
    topidx[t * 2] = i0; topidx[t * 2 + 1] = i1;
    tops[t * 2] = s0;  tops[t * 2 + 1] = e1 / (1.f + e1);
  }
}

// single block: counts -> padded offsets -> positions + inverse map + zero row
__global__ __launch_bounds__(1024) void k_route(
    const int* __restrict__ topidx, int* __restrict__ pos_of, int* __restrict__ off,
    int* __restrict__ tok_of, unsigned short* __restrict__ zrow)
{
  __shared__ int scnt[8], soff[9], sfill[8];
  int tid = threadIdx.x;
  if (tid < 8) { scnt[tid] = 0; sfill[tid] = 0; }
  if (tid < 384) ((unsigned*)zrow)[tid] = 0;
  for (int j = tid; j < CAP; j += 1024) tok_of[j] = -1;
  __syncthreads();
#pragma unroll
  for (int j = 0; j < 8; ++j)
    atomicAdd(&scnt[topidx[tid + j * 1024]], 1);
  __syncthreads();
  if (tid == 0) {
    int a = 0;
    for (int e = 0; e < 8; ++e) { soff[e] = a; off[e] = a; a += (scnt[e] + 127) & ~127; }
    soff[8] = a; off[8] = a;
  }
  __syncthreads();
#pragma unroll
  for (int j = 0; j < 8; ++j) {
    int i = tid + j * 1024;
    int e = topidx[i];
    int p = soff[e] + atomicAdd(&sfill[e], 1);
    pos_of[i] = p;
    tok_of[p] = i >> 1;
  }
}

__global__ void k_combine(const float* __restrict__ x1,
                          const unsigned short* __restrict__ y0h,
                          const unsigned short* __restrict__ y1h,
                          const int* __restrict__ pos_of, const float* __restrict__ tops,
                          float* __restrict__ out) {
  int t = blockIdx.x, tid = threadIdx.x;
  int p0 = pos_of[t * 2], p1 = pos_of[t * 2 + 1];
  float s0 = tops[t * 2], s1 = tops[t * 2 + 1];
  const float* xr = x1 + (size_t)t * DIM_;
  const unsigned short* a0 = y0h + (size_t)p0 * DIM_;
  const unsigned short* a1 = y1h + (size_t)p0 * DIM_;
  const unsigned short* b0 = y0h + (size_t)p1 * DIM_;
  const unsigned short* b1 = y1h + (size_t)p1 * DIM_;
  float* orow = out + (size_t)t * DIM_;
#pragma unroll
  for (int j = 0; j < 3; ++j) {
    int col = tid + j * 256;
    float ya = bf2f(a0[col]) + bf2f(a1[col]);
    float yb = bf2f(b0[col]) + bf2f(b1[col]);
    orow[col] = xr[col] + s0 * ya + s1 * yb;
  }
}

extern "C" void kernel_launch(void* const* d_in, const int* in_sizes, int n_in,
                              void* d_out, int out_size, void* d_ws, size_t ws_size,
                              hipStream_t stream) {
  const float* x     = (const float*)d_in[0];
  const float* ln1g  = (const float*)d_in[1];
  const float* ln1b  = (const float*)d_in[2];
  const float* qkvw  = (const float*)d_in[3];
  const float* projw = (const float*)d_in[4];
  const float* projb = (const float*)d_in[5];
  const float* ln2g  = (const float*)d_in[6];
  const float* ln2b  = (const float*)d_in[7];
  const float* gw    = (const float*)d_in[8];
  const float* gb    = (const float*)d_in[9];
  const float* w1    = (const float*)d_in[10];
  const float* b1    = (const float*)d_in[11];
  const float* w2    = (const float*)d_in[12];
  const float* b2    = (const float*)d_in[13];
  float* out = (float*)d_out;

  char* base = (char*)d_ws;
  unsigned short* hbf    = (unsigned short*)(base + 0);          // 6.29MB (reused as h2)
  unsigned short* qkvb   = (unsigned short*)(base + 6291456);    // 18.9MB
  unsigned short* abuf   = (unsigned short*)(base + 25165824);   // 6.29MB (reused as routing scratch)
  float*          x1     = (float*)(base + 31457280);            // 12.6MB
  unsigned short* hidden = (unsigned short*)(base + 44040192);   // 56.6MB
  unsigned short* ye0    = (unsigned short*)(base + 100663296);  // 14.2MB bf16
  unsigned short* ye1    = (unsigned short*)(base + 114819072);  // 14.2MB bf16

  const size_t FULL_NEED = 209190912;   // + bf16 weight copies
  const bool full = ws_size >= FULL_NEED;
  unsigned short *wqkvbf, *wprojbf, *w1bf = nullptr, *w2bf = nullptr;
  if (full) {
    wqkvbf  = (unsigned short*)(base + 128974848);
    wprojbf = (unsigned short*)(base + 132513792);
    w1bf    = (unsigned short*)(base + 133693440);
    w2bf    = (unsigned short*)(base + 171442176);
  } else {
    wqkvbf  = (unsigned short*)(base + 44040192);     // hidden region, free pre-ffn
    wprojbf = (unsigned short*)(base + 44040192 + 3538944);
  }
  // routing scratch lives in abuf's region (abuf dead after k_proj)
  char* small = base + 25165824;
  int*   topidx = (int*)small;                        // 32KB
  float* tops   = (float*)(small + 32768);            // 32KB
  int*   pos_of = (int*)(small + 65536);              // 32KB
  int*   off    = (int*)(small + 98304);              // 64B
  int*   tok_of = (int*)(small + 98368);              // 36.9KB
  unsigned short* zrow = (unsigned short*)(small + 135232);  // 1.5KB zeros
  unsigned short* h2 = hbf;

  k_cvtln<<<1152 + NTOK, 256, 0, stream>>>(qkvw, projw, wqkvbf, wprojbf,
                                           x, ln1g, ln1b, hbf);
  if (full)
    k_qkvcvt<true><<<576 + 18432, 256, 0, stream>>>(hbf, wqkvbf, qkvb,
                                                    w1, w2, w1bf, w2bf);
  else
    k_qkvcvt<false><<<576, 256, 0, stream>>>(hbf, wqkvbf, qkvb,
                                             nullptr, nullptr, nullptr, nullptr);
  k_attn<<<768, 256, 0, stream>>>(qkvb, abuf);
  k_proj<<<dim3(32, 6), 256, 0, stream>>>(abuf, wprojbf, projb, x, x1);
  k_ln2gate<<<NTOK, 256, 0, stream>>>(x1, ln2g, ln2b, gw, gb, h2, topidx, tops);
  k_route<<<1, 1024, 0, stream>>>(topidx, pos_of, off, tok_of, zrow);
  if (full) {
    k_ffn1<true><<<1728, 256, 0, stream>>>(h2, w1bf, b1, off, tok_of, zrow, hidden);
    k_ffn2<true><<<864, 256, 0, stream>>>(hidden, w2bf, b2, off, ye0, ye1);
  } else {
    k_ffn1<false><<<1728, 256, 0, stream>>>(h2, w1, b1, off, tok_of, zrow, hidden);
    k_ffn2<false><<<864, 256, 0, stream>>>(hidden, w2, b2, off, ye0, ye1);
  }
  k_combine<<<NTOK, 256, 0, stream>>>(x1, ye0, ye1, pos_of, tops, out);
}